// Round 21
// baseline (116.129 us; speedup 1.0000x reference)
//
#include <hip/hip_runtime.h>
#include <hip/hip_bf16.h>

typedef __attribute__((ext_vector_type(8))) short short8;
typedef __attribute__((ext_vector_type(4))) short short4_t;
typedef __attribute__((ext_vector_type(4))) float f32x4;
typedef unsigned short ushort_t;

#define DEV __device__ __forceinline__

DEV ushort_t f2bf(float f) {
    unsigned u = __builtin_bit_cast(unsigned, f);
    u = u + 0x7fffu + ((u >> 16) & 1u);   // RNE
    return (ushort_t)(u >> 16);
}

DEV unsigned pk_bf16(float lo, float hi) {
    __hip_bfloat162 h = __float22bfloat162_rn(make_float2(lo, hi));
    unsigned u;
    __builtin_memcpy(&u, &h, sizeof(u));
    return u;
}

// raw v_exp_f32: single TRANS-pipe instr; exact in our argument range.
DEV float fast_exp2(float x) {
#if __has_builtin(__builtin_amdgcn_exp2f)
    return __builtin_amdgcn_exp2f(x);
#else
    float r;
    asm("v_exp_f32 %0, %1" : "=v"(r) : "v"(x));
    return r;
#endif
}

DEV short8 ld8(const ushort_t* p) { return *reinterpret_cast<const short8*>(p); }

#define SCL_F 0.18033688011112042f   // 0.125 * log2(e), prefolded into Q

// ---------------------------------------------------------------------------
// Fused prep: one dispatch handles cvt(i1), cvt(i2), tcvt(Wq), tcvt(Wkv).
//   blocks [0,2048)     : i1  f32 -> bf16 (A1)
//   blocks [2048,4096)  : i2  f32 -> bf16 (A2)
//   blocks [4096,4352)  : Wq  [1024,1024] -> Wqt  [n][k] bf16
//   blocks [4352,4864)  : Wkv [1024,2048] -> Wkvt [n][k] bf16
// ---------------------------------------------------------------------------
__global__ __launch_bounds__(256)
void prep_all(const float* __restrict__ i1, const float* __restrict__ i2,
              const float* __restrict__ Wq, const float* __restrict__ Wkv,
              ushort_t* __restrict__ A1, ushort_t* __restrict__ A2,
              ushort_t* __restrict__ Wqt, ushort_t* __restrict__ Wkvt)
{
    __shared__ ushort_t tile[64][72];
    const int t = threadIdx.x;
    const int id = blockIdx.x;

    if (id < 4096) {
        // elementwise cvt: 2048 blocks per input, 8 elems/thread
        const float* in = (id < 2048) ? i1 : i2;
        ushort_t* out = (id < 2048) ? A1 : A2;
        const size_t i = ((size_t)(id & 2047) * 256 + t) * 8;
        const float4 a = *reinterpret_cast<const float4*>(in + i);
        const float4 b = *reinterpret_cast<const float4*>(in + i + 4);
        short8 v;
        v[0] = (short)f2bf(a.x); v[1] = (short)f2bf(a.y);
        v[2] = (short)f2bf(a.z); v[3] = (short)f2bf(a.w);
        v[4] = (short)f2bf(b.x); v[5] = (short)f2bf(b.y);
        v[6] = (short)f2bf(b.z); v[7] = (short)f2bf(b.w);
        *reinterpret_cast<short8*>(out + i) = v;
        return;
    }

    // weight transpose: W[K][N] f32 -> Wt[N][K] bf16, 64x64 tiles via LDS
    const float* W;
    ushort_t* Wt;
    int N, nx, ky;
    if (id < 4352) {
        const int r = id - 4096;              // 256 blocks: 16 nx x 16 ky
        W = Wq; Wt = Wqt; N = 1024;
        nx = (r & 15) * 64; ky = (r >> 4) * 64;
    } else {
        const int r = id - 4352;              // 512 blocks: 32 nx x 16 ky
        W = Wkv; Wt = Wkvt; N = 2048;
        nx = (r & 31) * 64; ky = (r >> 5) * 64;
    }
    const int rr = t >> 2, q = (t & 3) * 16;
    const float* src = W + (size_t)(ky + rr) * N + nx + q;
#pragma unroll
    for (int i = 0; i < 4; ++i) {
        const float4 v = *reinterpret_cast<const float4*>(src + 4 * i);
        tile[rr][q + 4 * i + 0] = f2bf(v.x);
        tile[rr][q + 4 * i + 1] = f2bf(v.y);
        tile[rr][q + 4 * i + 2] = f2bf(v.z);
        tile[rr][q + 4 * i + 3] = f2bf(v.w);
    }
    __syncthreads();
    short8 o0, o1;
#pragma unroll
    for (int i = 0; i < 8; ++i) {
        o0[i] = (short)tile[q + i][rr];
        o1[i] = (short)tile[q + 8 + i][rr];
    }
    ushort_t* dst = Wt + (size_t)(nx + rr) * 1024 + ky + q;
    *reinterpret_cast<short8*>(dst) = o0;
    *reinterpret_cast<short8*>(dst + 8) = o1;
}

// ---------------------------------------------------------------------------
// Fused projections: nblk<8 -> Q = A1 @ WqT; else KV = A2 @ WkvT.
// 1D grid (768) with XCD swizzle (r19-proven). Q pre-scaled by SCL_F.
// Double-buffered LDS: ONE barrier per K-step (write(it)->bar->compute(it);
// write(it+2) into buf[it&1] is ordered after bar(it+1) > all compute(it)).
// ---------------------------------------------------------------------------
__global__ __launch_bounds__(256, 2)
void proj_all(const ushort_t* __restrict__ A1, const ushort_t* __restrict__ A2,
              const ushort_t* __restrict__ Wqt, const ushort_t* __restrict__ Wkvt,
              const float* __restrict__ bqv, const float* __restrict__ bkv,
              ushort_t* __restrict__ Qr, ushort_t* __restrict__ Kr,
              ushort_t* __restrict__ Vt)
{
    __shared__ ushort_t As[2][128 * 72];
    __shared__ ushort_t Bs[2][128 * 72];

    const int t = threadIdx.x;
    const int lane = t & 63;
    const int wv = t >> 6;
    const int wr = wv >> 1, wc = wv & 1;
    const int c = lane & 15, g = lane >> 4;

    const int lid = blockIdx.x;
    const int m0i = (lid & 7) + 8 * ((lid >> 3) & 3);
    const int nblk = lid >> 5;
    const int m0 = m0i * 128;

    const ushort_t* A;
    const ushort_t* Wt;
    const float* bias;
    int n0;
    if (nblk < 8) { A = A1; Wt = Wqt;  bias = bqv; n0 = nblk * 128; }
    else          { A = A2; Wt = Wkvt; bias = bkv; n0 = (nblk - 8) * 128; }
    const bool isQ = (nblk < 8);
    const float qscale = isQ ? SCL_F : 1.0f;

    f32x4 acc[4][4];
    const f32x4 zero4 = {0.f, 0.f, 0.f, 0.f};
#pragma unroll
    for (int mi = 0; mi < 4; ++mi)
#pragma unroll
        for (int ni = 0; ni < 4; ++ni) acc[mi][ni] = zero4;

    const int srow[4] = { (t + 0)   >> 3, (t + 256) >> 3, (t + 512) >> 3, (t + 768) >> 3 };
    const int skq     = (t & 7) * 8;

    short8 a_reg[4], b_reg[4];
#pragma unroll
    for (int rep = 0; rep < 4; ++rep) {
        a_reg[rep] = ld8(A  + (size_t)(m0 + srow[rep]) * 1024 + skq);
        b_reg[rep] = ld8(Wt + (size_t)(n0 + srow[rep]) * 1024 + skq);
    }

    for (int it = 0; it < 16; ++it) {
        ushort_t* Asb = As[it & 1];
        ushort_t* Bsb = Bs[it & 1];
#pragma unroll
        for (int rep = 0; rep < 4; ++rep) {
            *reinterpret_cast<short8*>(&Asb[srow[rep] * 72 + skq]) = a_reg[rep];
            *reinterpret_cast<short8*>(&Bsb[srow[rep] * 72 + skq]) = b_reg[rep];
        }
        __syncthreads();
        if (it < 15) {
            const int k1 = (it + 1) * 64;
#pragma unroll
            for (int rep = 0; rep < 4; ++rep) {
                a_reg[rep] = ld8(A  + (size_t)(m0 + srow[rep]) * 1024 + k1 + skq);
                b_reg[rep] = ld8(Wt + (size_t)(n0 + srow[rep]) * 1024 + k1 + skq);
            }
        }
#pragma unroll
        for (int kk = 0; kk < 64; kk += 32) {
            short8 afr[4], bfr[4];
#pragma unroll
            for (int mi = 0; mi < 4; ++mi)
                afr[mi] = ld8(&Asb[(wr * 64 + mi * 16 + c) * 72 + kk + 8 * g]);
#pragma unroll
            for (int ni = 0; ni < 4; ++ni)
                bfr[ni] = ld8(&Bsb[(wc * 64 + ni * 16 + c) * 72 + kk + 8 * g]);
#pragma unroll
            for (int mi = 0; mi < 4; ++mi)
#pragma unroll
                for (int ni = 0; ni < 4; ++ni)
                    acc[mi][ni] = __builtin_amdgcn_mfma_f32_16x16x32_bf16(
                        afr[mi], bfr[ni], acc[mi][ni], 0, 0, 0);
        }
    }

#pragma unroll
    for (int mi = 0; mi < 4; ++mi) {
#pragma unroll
        for (int ni = 0; ni < 4; ++ni) {
            const int n = n0 + wc * 64 + ni * 16 + c;
            const float bb = bias[n];
#pragma unroll
            for (int j = 0; j < 4; ++j) {
                const int m = m0 + wr * 64 + mi * 16 + 4 * g + j;
                const int b = m >> 11, s = m & 2047;
                const ushort_t val = f2bf((acc[mi][ni][j] + bb) * qscale);
                if (isQ) {
                    Qr[((size_t)((b * 16 + (n >> 6)) * 2048 + s)) * 64 + (n & 63)] = val;
                } else if (n < 1024) {
                    Kr[((size_t)((b * 16 + (n >> 6)) * 2048 + s)) * 64 + (n & 63)] = val;
                } else {
                    const int np = n - 1024;
                    Vt[(size_t)((b * 16 + (np >> 6)) * 64 + (np & 63)) * 2048 + s] = val;
                }
            }
        }
    }
}

// ---------------------------------------------------------------------------
// Fallback projection (r3/r8-proven): used if ws_size is too small for prep.
// ---------------------------------------------------------------------------
__global__ __launch_bounds__(256)
void proj_gemm(const float* __restrict__ A, const float* __restrict__ W,
               const float* __restrict__ bias, int N,
               ushort_t* __restrict__ outRow, ushort_t* __restrict__ outT)
{
    __shared__ ushort_t As[128 * 72];
    __shared__ ushort_t Bt[128 * 72];

    const int t = threadIdx.x;
    const int lane = t & 63;
    const int wv = t >> 6;
    const int wr = wv >> 1, wc = wv & 1;
    const int c = lane & 15, g = lane >> 4;
    const int m0 = blockIdx.y * 128, n0 = blockIdx.x * 128;
    const float qscale = (outT == nullptr) ? SCL_F : 1.0f;

    f32x4 acc[4][4];
    const f32x4 zero4 = {0.f, 0.f, 0.f, 0.f};
#pragma unroll
    for (int mi = 0; mi < 4; ++mi)
#pragma unroll
        for (int ni = 0; ni < 4; ++ni) acc[mi][ni] = zero4;

    for (int it = 0; it < 16; ++it) {
        const int k0 = it * 64;
        {
            const int kq = (t & 15) * 4;
            int r = t >> 4;
#pragma unroll
            for (int rep = 0; rep < 8; ++rep, r += 16) {
                float4 v = *reinterpret_cast<const float4*>(
                    A + (size_t)(m0 + r) * 1024 + k0 + kq);
                ushort_t* dst = &As[r * 72 + kq];
                dst[0] = f2bf(v.x); dst[1] = f2bf(v.y);
                dst[2] = f2bf(v.z); dst[3] = f2bf(v.w);
            }
        }
        {
            const int nq = (t & 31) * 4;
            const int kr = t >> 5;
#pragma unroll
            for (int rep = 0; rep < 8; ++rep) {
                const int k = kr + 8 * rep;
                float4 v = *reinterpret_cast<const float4*>(
                    W + (size_t)(k0 + k) * N + n0 + nq);
                Bt[(nq + 0) * 72 + k] = f2bf(v.x);
                Bt[(nq + 1) * 72 + k] = f2bf(v.y);
                Bt[(nq + 2) * 72 + k] = f2bf(v.z);
                Bt[(nq + 3) * 72 + k] = f2bf(v.w);
            }
        }
        __syncthreads();
#pragma unroll
        for (int kk = 0; kk < 64; kk += 32) {
            short8 afr[4], bfr[4];
#pragma unroll
            for (int mi = 0; mi < 4; ++mi)
                afr[mi] = ld8(&As[(wr * 64 + mi * 16 + c) * 72 + kk + 8 * g]);
#pragma unroll
            for (int ni = 0; ni < 4; ++ni)
                bfr[ni] = ld8(&Bt[(wc * 64 + ni * 16 + c) * 72 + kk + 8 * g]);
#pragma unroll
            for (int mi = 0; mi < 4; ++mi)
#pragma unroll
                for (int ni = 0; ni < 4; ++ni)
                    acc[mi][ni] = __builtin_amdgcn_mfma_f32_16x16x32_bf16(
                        afr[mi], bfr[ni], acc[mi][ni], 0, 0, 0);
        }
        __syncthreads();
    }

#pragma unroll
    for (int mi = 0; mi < 4; ++mi) {
#pragma unroll
        for (int ni = 0; ni < 4; ++ni) {
            const int n = n0 + wc * 64 + ni * 16 + c;
            const float bb = bias[n];
#pragma unroll
            for (int j = 0; j < 4; ++j) {
                const int m = m0 + wr * 64 + mi * 16 + 4 * g + j;
                const int b = m >> 11, s = m & 2047;
                const ushort_t val = f2bf((acc[mi][ni][j] + bb) * qscale);
                if (outT != nullptr && n >= 1024) {
                    const int np = n - 1024;
                    const int hh = np >> 6, d = np & 63;
                    outT[(size_t)((b * 16 + hh) * 64 + d) * 2048 + s] = val;
                } else {
                    const int hh = n >> 6, d = n & 63;
                    outRow[((size_t)((b * 16 + hh) * 2048 + s)) * 64 + d] = val;
                }
            }
        }
    }
}

// ---------------------------------------------------------------------------
// Flash attention (r19 champion): 2-tile LDS pipeline, stats-as-MFMA,
// setprio'd MFMA clusters, XOR-swizzled LDS.
// ---------------------------------------------------------------------------
DEV void tile_compute(const ushort_t* __restrict__ Ks, const ushort_t* __restrict__ Vs,
                      const ushort_t* __restrict__ Sts, int c, int g,
                      const short8 (&bq)[2][2],
                      f32x4 (&accv)[2][4], f32x4 (&stat)[2])
{
    const f32x4 zero4 = {0.f, 0.f, 0.f, 0.f};
    const int kxor = (c & 7) << 3;
    const int vxor = (c & 7) << 2;

    short8 KC[2][2];
#pragma unroll
    for (int ct = 0; ct < 2; ++ct)
#pragma unroll
        for (int st = 0; st < 2; ++st)
            KC[ct][st] = ld8(&Ks[(ct * 16 + c) * 64 + ((st * 32 + 8 * g) ^ kxor)]);
    short8 VC[4];
#pragma unroll
    for (int dt = 0; dt < 4; ++dt) {
        const short4_t vlo = *reinterpret_cast<const short4_t*>(
            &Vs[(dt * 16 + c) * 32 + ((4 * g) ^ vxor)]);
        const short4_t vhi = *reinterpret_cast<const short4_t*>(
            &Vs[(dt * 16 + c) * 32 + ((4 * g + 16) ^ vxor)]);
        VC[dt] = __builtin_shufflevector(vlo, vhi, 0, 1, 2, 3, 4, 5, 6, 7);
    }
    const short4_t slo = *reinterpret_cast<const short4_t*>(
        &Sts[c * 32 + ((4 * g) ^ vxor)]);
    const short4_t shi = *reinterpret_cast<const short4_t*>(
        &Sts[c * 32 + ((4 * g + 16) ^ vxor)]);
    const short8 stf = __builtin_shufflevector(slo, shi, 0, 1, 2, 3, 4, 5, 6, 7);

    // QK^T (swapped): lane holds S^T[kv=16ct+4g+j][q=c] (already * SCL)
    f32x4 sc[2][2];
    __builtin_amdgcn_s_setprio(1);
#pragma unroll
    for (int qt = 0; qt < 2; ++qt)
#pragma unroll
        for (int ct = 0; ct < 2; ++ct) {
            f32x4 z = zero4;
            z = __builtin_amdgcn_mfma_f32_16x16x32_bf16(KC[ct][0], bq[qt][0], z, 0, 0, 0);
            z = __builtin_amdgcn_mfma_f32_16x16x32_bf16(KC[ct][1], bq[qt][1], z, 0, 0, 0);
            sc[qt][ct] = z;
        }
    __builtin_amdgcn_s_setprio(0);

    // fixed-max softmax: P = exp2(sc) -> bf16
    short8 pa[2];
#pragma unroll
    for (int qt = 0; qt < 2; ++qt) {
        float e[2][4];
#pragma unroll
        for (int ct = 0; ct < 2; ++ct)
#pragma unroll
            for (int j = 0; j < 4; ++j)
                e[ct][j] = fast_exp2(sc[qt][ct][j]);
        int4 w;
        w.x = (int)pk_bf16(e[0][0], e[0][1]);
        w.y = (int)pk_bf16(e[0][2], e[0][3]);
        w.z = (int)pk_bf16(e[1][0], e[1][1]);
        w.w = (int)pk_bf16(e[1][2], e[1][3]);
        pa[qt] = __builtin_bit_cast(short8, w);
    }

    // stats + PV^T (A operands gathered in the same kv-slot permutation as P)
    __builtin_amdgcn_s_setprio(1);
#pragma unroll
    for (int qt = 0; qt < 2; ++qt)
        stat[qt] = __builtin_amdgcn_mfma_f32_16x16x32_bf16(stf, pa[qt], stat[qt], 0, 0, 0);
#pragma unroll
    for (int dt = 0; dt < 4; ++dt) {
        accv[0][dt] = __builtin_amdgcn_mfma_f32_16x16x32_bf16(VC[dt], pa[0], accv[0][dt], 0, 0, 0);
        accv[1][dt] = __builtin_amdgcn_mfma_f32_16x16x32_bf16(VC[dt], pa[1], accv[1][dt], 0, 0, 0);
    }
    __builtin_amdgcn_s_setprio(0);
}

DEV void pair_body(const ushort_t* __restrict__ Kh, const ushort_t* __restrict__ Vh,
                   const float* __restrict__ crb, int kvA, int kvB,
                   const ushort_t* KsC0, const ushort_t* VsC0, const ushort_t* StC0,
                   const ushort_t* KsC1, const ushort_t* VsC1, const ushort_t* StC1,
                   ushort_t* KsN0, ushort_t* VsN0, ushort_t* StN0,
                   ushort_t* KsN1, ushort_t* VsN1, ushort_t* StN1,
                   int t, int c, int g, int rk, int ck, int rv, int cv,
                   int kaddr, int vaddr0, int vaddr1,
                   const short8 (&bq)[2][2],
                   f32x4 (&accv)[2][4], f32x4 (&stat)[2])
{
    // prefetch next two tiles (global -> reg); cr rows by threads t<128
    const short8 kregA = ld8(Kh + (size_t)(kvA + rk) * 64 + ck);
    const short8 vregA = ld8(Vh + (size_t)rv * 2048 + kvA + cv);
    const short8 kregB = ld8(Kh + (size_t)(kvB + rk) * 64 + ck);
    const short8 vregB = ld8(Vh + (size_t)rv * 2048 + kvB + cv);
    ushort_t crsh = 0; int staddr = 0;
    if (t < 128) {
        const int kvX = (t & 64) ? kvB : kvA;
        const int row = 1 + ((t >> 5) & 1);
        const float v = crb[(size_t)(kvX + (t & 31)) * 2 + (row - 1)];
        crsh = f2bf(v);
        staddr = row * 32 + ((t & 31) ^ ((row & 7) << 2));
    }
    __builtin_amdgcn_sched_barrier(0);

    // two independent tile computations (compiler interleaves for ILP)
    tile_compute(KsC0, VsC0, StC0, c, g, bq, accv, stat);
    tile_compute(KsC1, VsC1, StC1, c, g, bq, accv, stat);

    // write staged tiles into the next buffer group; one barrier per 64 kv
    *reinterpret_cast<short8*>(&KsN0[kaddr]) = kregA;
    *reinterpret_cast<short8*>(&KsN1[kaddr]) = kregB;
    *reinterpret_cast<short4_t*>(&VsN0[vaddr0]) = __builtin_shufflevector(vregA, vregA, 0, 1, 2, 3);
    *reinterpret_cast<short4_t*>(&VsN0[vaddr1]) = __builtin_shufflevector(vregA, vregA, 4, 5, 6, 7);
    *reinterpret_cast<short4_t*>(&VsN1[vaddr0]) = __builtin_shufflevector(vregB, vregB, 0, 1, 2, 3);
    *reinterpret_cast<short4_t*>(&VsN1[vaddr1]) = __builtin_shufflevector(vregB, vregB, 4, 5, 6, 7);
    if (t < 128) ((t & 64) ? StN1 : StN0)[staddr] = crsh;
    __syncthreads();
}

__global__ __launch_bounds__(256, 2)
void attn_kernel(const ushort_t* __restrict__ Qr, const ushort_t* __restrict__ Kr,
                 const ushort_t* __restrict__ Vt, const float* __restrict__ cr,
                 const float* __restrict__ Wmo, const float* __restrict__ bmo,
                 float* __restrict__ out)
{
    // shorts: K 4x2048 @0; V 4x2048 @8192; St 4x512 @16384. 36864 B total.
    __shared__ ushort_t smem[18432];
    ushort_t* K0 = smem;            ushort_t* K1 = smem + 2048;
    ushort_t* K2 = smem + 4096;     ushort_t* K3 = smem + 6144;
    ushort_t* V0 = smem + 8192;     ushort_t* V1 = smem + 10240;
    ushort_t* V2 = smem + 12288;    ushort_t* V3 = smem + 14336;
    ushort_t* S0 = smem + 16384;    ushort_t* S1 = smem + 16896;
    ushort_t* S2 = smem + 17408;    ushort_t* S3 = smem + 17920;

    const int t = threadIdx.x;
    const int w = t >> 6, lane = t & 63;
    const int c = lane & 15, g = lane >> 4;
    const int rk = t >> 3, ck = (t & 7) * 8;
    const int rv = t >> 2, cv = (t & 3) * 8;
    const int kaddr  = rk * 64 + (ck ^ ((rk & 7) << 3));
    const int vaddr0 = rv * 32 + (cv ^ ((rv & 7) << 2));
    const int vaddr1 = rv * 32 + ((cv + 4) ^ ((rv & 7) << 2));

    // XCD swizzle: gid%8 ~ XCD; each XCD sees 4 distinct (b,h) pairs.
    const int gid = blockIdx.x;
    const int bh = (gid & 7) + 8 * ((gid >> 3) & 3);
    const int xt = gid >> 5;
    const int b = bh >> 4, hh = bh & 15;
    const int qb = xt * 128 + w * 32;

    const ushort_t* Qh = Qr + (size_t)bh * (2048 * 64);
    const ushort_t* Kh = Kr + (size_t)bh * (2048 * 64);
    const ushort_t* Vh = Vt + (size_t)bh * (64 * 2048);
    const float*   crb = cr + (size_t)b * (2048 * 2);

    short8 bq[2][2];
#pragma unroll
    for (int qt = 0; qt < 2; ++qt)
#pragma unroll
        for (int st = 0; st < 2; ++st)
            bq[qt][st] = ld8(Qh + (size_t)(qb + qt * 16 + c) * 64 + st * 32 + 8 * g);

    f32x4 accv[2][4];
    f32x4 stat[2];
    const f32x4 zero4 = {0.f, 0.f, 0.f, 0.f};
#pragma unroll
    for (int qt = 0; qt < 2; ++qt) {
        stat[qt] = zero4;
#pragma unroll
        for (int dt = 0; dt < 4; ++dt) accv[qt][dt] = zero4;
    }

    // init static St rows (0 -> ones, 3..15 -> zero) for all 4 groups
    for (int idx = t; idx < 2048; idx += 256) {
        const int row = (idx >> 5) & 15;
        if (row != 1 && row != 2)
            smem[16384 + idx] = (row == 0) ? (ushort_t)0x3F80 : (ushort_t)0;
    }

    // prologue: stage tiles kv=0 (group0) and kv=32 (group1)
    {
        const short8 kA = ld8(Kh + (size_t)rk * 64 + ck);
        const short8 vA = ld8(Vh + (size_t)rv * 2048 + cv);
        const short8 kB = ld8(Kh + (size_t)(32 + rk) * 64 + ck);
        const short8 vB = ld8(Vh + (size_t)rv * 2048 + 32 + cv);
        *reinterpret_cast<short8*>(&K0[kaddr]) = kA;
        *reinterpret_cast<short8*>(&K1[kaddr]) = kB;
        *reinterpret_cast<short4_t*>(&V0[vaddr0]) = __builtin_shufflevector(vA, vA, 0, 1, 2, 3);
        *reinterpret_cast<short4_t*>(&V0[vaddr1]) = __builtin_shufflevector(vA, vA, 4, 5, 6, 7);
        *reinterpret_cast<short4_t*>(&V1[vaddr0]) = __builtin_shufflevector(vB, vB, 0, 1, 2, 3);
        *reinterpret_cast<short4_t*>(&V1[vaddr1]) = __builtin_shufflevector(vB, vB, 4, 5, 6, 7);
        if (t < 128) {
            const int kvX = (t & 64) ? 32 : 0;
            const int row = 1 + ((t >> 5) & 1);
            const float v = crb[(size_t)(kvX + (t & 31)) * 2 + (row - 1)];
            ((t & 64) ? S1 : S0)[row * 32 + ((t & 31) ^ ((row & 7) << 2))] = f2bf(v);
        }
    }
    __syncthreads();

    for (int i = 0; i < 16; ++i) {
        const int base = i * 128;
        pair_body(Kh, Vh, crb, base + 64, base + 96,
                  K0, V0, S0, K1, V1, S1,
                  K2, V2, S2, K3, V3, S3,
                  t, c, g, rk, ck, rv, cv, kaddr, vaddr0, vaddr1,
                  bq, accv, stat);
        pair_body(Kh, Vh, crb, (base + 128) & 2047, (base + 160) & 2047,
                  K2, V2, S2, K3, V3, S3,
                  K0, V0, S0, K1, V1, S1,
                  t, c, g, rk, ck, rv, cv, kaddr, vaddr0, vaddr1,
                  bq, accv, stat);
    }

    // stats live in lane (c, g=0): reg 0=l, 1=a0, 2=a1. Broadcast to all g.
    float lst[2], a0s[2], a1s[2];
#pragma unroll
    for (int qt = 0; qt < 2; ++qt) {
        lst[qt] = __shfl(stat[qt][0], c, 64);
        a0s[qt] = __shfl(stat[qt][1], c, 64);
        a1s[qt] = __shfl(stat[qt][2], c, 64);
    }

    // epilogue: accv[qt][dt] reg j -> q = qb+qt*16+c, d = dt*16+4g+j
#pragma unroll
    for (int qt = 0; qt < 2; ++qt) {
        const int q = qb + qt * 16 + c;
        const float inv = 1.f / lst[qt];
        const float a0 = a0s[qt] * inv, a1 = a1s[qt] * inv;
#pragma unroll
        for (int dt = 0; dt < 4; ++dt) {
            const int d = hh * 64 + dt * 16 + 4 * g;
            const float4 w0 = *reinterpret_cast<const float4*>(Wmo + d);
            const float4 w1 = *reinterpret_cast<const float4*>(Wmo + 1024 + d);
            const float4 bm = *reinterpret_cast<const float4*>(bmo + d);
            const size_t oidx = ((size_t)(b * 2048 + q)) * 1024 + d;
            float4 hv, mv;
            hv.x = accv[qt][dt][0] * inv; hv.y = accv[qt][dt][1] * inv;
            hv.z = accv[qt][dt][2] * inv; hv.w = accv[qt][dt][3] * inv;
            mv.x = a0 * w0.x + a1 * w1.x + bm.x;
            mv.y = a0 * w0.y + a1 * w1.y + bm.y;
            mv.z = a0 * w0.z + a1 * w1.z + bm.z;
            mv.w = a0 * w0.w + a1 * w1.w + bm.w;
            *reinterpret_cast<float4*>(out + oidx) = hv;
            *reinterpret_cast<float4*>(out + 4194304 + oidx) = mv;
        }
    }
}

// ---------------------------------------------------------------------------
extern "C" void kernel_launch(void* const* d_in, const int* in_sizes, int n_in,
                              void* d_out, int out_size, void* d_ws, size_t ws_size,
                              hipStream_t stream)
{
    const float* i1  = (const float*)d_in[0];
    const float* i2  = (const float*)d_in[1];
    const float* cr  = (const float*)d_in[2];
    const float* Wq  = (const float*)d_in[3];
    const float* bq  = (const float*)d_in[4];
    const float* Wkv = (const float*)d_in[5];
    const float* bkv = (const float*)d_in[6];
    const float* Wmo = (const float*)d_in[7];
    const float* bmo = (const float*)d_in[8];
    float* out = (float*)d_out;

    ushort_t* Qr = (ushort_t*)d_ws;          // [2,16,2048,64] bf16 (8 MB)
    ushort_t* Kr = Qr + 4194304;             // (8 MB)
    ushort_t* Vt = Kr + 4194304;             // (8 MB)

    // fast path needs 46 MB of ws: + A1(8) A2(8) Wqt(2) Wkvt(4)
    if (ws_size >= 48234496ULL) {
        ushort_t* A1   = Vt + 4194304;
        ushort_t* A2   = A1 + 4194304;
        ushort_t* Wqt  = A2 + 4194304;
        ushort_t* Wkvt = Wqt + 1048576;
        prep_all<<<dim3(4864), dim3(256), 0, stream>>>(i1, i2, Wq, Wkv, A1, A2, Wqt, Wkvt);
        proj_all<<<dim3(768), dim3(256), 0, stream>>>(A1, A2, Wqt, Wkvt, bq, bkv, Qr, Kr, Vt);
    } else {
        proj_gemm<<<dim3(8, 32), dim3(256), 0, stream>>>(i1, Wq, bq, 1024, Qr, nullptr);
        proj_gemm<<<dim3(16, 32), dim3(256), 0, stream>>>(i2, Wkv, bkv, 2048, Kr, Vt);
    }
    attn_kernel<<<dim3(512), dim3(256), 0, stream>>>(Qr, Kr, Vt, cr, Wmo, bmo, out);
}

// Round 22
// 110.787 us; speedup vs baseline: 1.0482x; 1.0482x over previous
//
#include <hip/hip_runtime.h>
#include <hip/hip_bf16.h>

typedef __attribute__((ext_vector_type(8))) short short8;
typedef __attribute__((ext_vector_type(4))) short short4_t;
typedef __attribute__((ext_vector_type(4))) float f32x4;
typedef unsigned short ushort_t;

#define DEV __device__ __forceinline__

DEV ushort_t f2bf(float f) {
    unsigned u = __builtin_bit_cast(unsigned, f);
    u = u + 0x7fffu + ((u >> 16) & 1u);   // RNE
    return (ushort_t)(u >> 16);
}

DEV unsigned pk_bf16(float lo, float hi) {
    __hip_bfloat162 h = __float22bfloat162_rn(make_float2(lo, hi));
    unsigned u;
    __builtin_memcpy(&u, &h, sizeof(u));
    return u;
}

// raw v_exp_f32: single TRANS-pipe instr; exact in our argument range.
DEV float fast_exp2(float x) {
#if __has_builtin(__builtin_amdgcn_exp2f)
    return __builtin_amdgcn_exp2f(x);
#else
    float r;
    asm("v_exp_f32 %0, %1" : "=v"(r) : "v"(x));
    return r;
#endif
}

DEV short8 ld8(const ushort_t* p) { return *reinterpret_cast<const short8*>(p); }

#define SCL_F 0.18033688011112042f   // 0.125 * log2(e), prefolded into Q

// ---------------------------------------------------------------------------
// prep: W[K][N] f32 -> Wt[N][K] bf16 (64x64 tiles via LDS)
// ---------------------------------------------------------------------------
__global__ __launch_bounds__(256)
void tcvt_bf16(const float* __restrict__ W, ushort_t* __restrict__ Wt, int K, int N)
{
    __shared__ ushort_t tile[64][72];
    const int t = threadIdx.x;
    const int nx = blockIdx.x * 64, ky = blockIdx.y * 64;
    const int r = t >> 2, q = (t & 3) * 16;

    const float* src = W + (size_t)(ky + r) * N + nx + q;
#pragma unroll
    for (int i = 0; i < 4; ++i) {
        const float4 v = *reinterpret_cast<const float4*>(src + 4 * i);
        tile[r][q + 4 * i + 0] = f2bf(v.x);
        tile[r][q + 4 * i + 1] = f2bf(v.y);
        tile[r][q + 4 * i + 2] = f2bf(v.z);
        tile[r][q + 4 * i + 3] = f2bf(v.w);
    }
    __syncthreads();
    short8 o0, o1;
#pragma unroll
    for (int i = 0; i < 8; ++i) {
        o0[i] = (short)tile[q + i][r];
        o1[i] = (short)tile[q + 8 + i][r];
    }
    ushort_t* dst = Wt + (size_t)(nx + r) * K + ky + q;
    *reinterpret_cast<short8*>(dst) = o0;
    *reinterpret_cast<short8*>(dst + 8) = o1;
}

// ---------------------------------------------------------------------------
// Fused projections: nblk<8 -> Q = i1 @ WqT; else KV = i2 @ WkvT.
// 1D grid (768) with XCD swizzle (r19-proven): all 24 blocks sharing an m0
// A-panel land on one XCD, so the f32 A re-reads stay L2-resident -- this is
// the r18 fused-cvt retried WITH the swizzle. A converted during staging
// (pk RNE == f2bf RNE). Q pre-scaled by SCL_F. Single-buffered LDS (r19).
// ---------------------------------------------------------------------------
__global__ __launch_bounds__(256, 2)
void proj_all(const float* __restrict__ i1, const float* __restrict__ i2,
              const ushort_t* __restrict__ Wqt, const ushort_t* __restrict__ Wkvt,
              const float* __restrict__ bqv, const float* __restrict__ bkv,
              ushort_t* __restrict__ Qr, ushort_t* __restrict__ Kr,
              ushort_t* __restrict__ Vt)
{
    __shared__ ushort_t As[128 * 72];
    __shared__ ushort_t Bs[128 * 72];

    const int t = threadIdx.x;
    const int lane = t & 63;
    const int wv = t >> 6;
    const int wr = wv >> 1, wc = wv & 1;
    const int c = lane & 15, g = lane >> 4;

    const int lid = blockIdx.x;
    const int m0i = (lid & 7) + 8 * ((lid >> 3) & 3);
    const int nblk = lid >> 5;
    const int m0 = m0i * 128;

    const float* Af;
    const ushort_t* Wt;
    const float* bias;
    int n0;
    if (nblk < 8) { Af = i1; Wt = Wqt;  bias = bqv; n0 = nblk * 128; }
    else          { Af = i2; Wt = Wkvt; bias = bkv; n0 = (nblk - 8) * 128; }
    const bool isQ = (nblk < 8);
    const float qscale = isQ ? SCL_F : 1.0f;

    f32x4 acc[4][4];
    const f32x4 zero4 = {0.f, 0.f, 0.f, 0.f};
#pragma unroll
    for (int mi = 0; mi < 4; ++mi)
#pragma unroll
        for (int ni = 0; ni < 4; ++ni) acc[mi][ni] = zero4;

    const int srow[4] = { (t + 0)   >> 3, (t + 256) >> 3, (t + 512) >> 3, (t + 768) >> 3 };
    const int skq     = (t & 7) * 8;

    float4 a_lo[4], a_hi[4];
    short8 b_reg[4];
#pragma unroll
    for (int rep = 0; rep < 4; ++rep) {
        const float* src = Af + (size_t)(m0 + srow[rep]) * 1024 + skq;
        a_lo[rep] = *reinterpret_cast<const float4*>(src);
        a_hi[rep] = *reinterpret_cast<const float4*>(src + 4);
        b_reg[rep] = ld8(Wt + (size_t)(n0 + srow[rep]) * 1024 + skq);
    }

    for (int it = 0; it < 16; ++it) {
#pragma unroll
        for (int rep = 0; rep < 4; ++rep) {
            int4 wvp;
            wvp.x = (int)pk_bf16(a_lo[rep].x, a_lo[rep].y);
            wvp.y = (int)pk_bf16(a_lo[rep].z, a_lo[rep].w);
            wvp.z = (int)pk_bf16(a_hi[rep].x, a_hi[rep].y);
            wvp.w = (int)pk_bf16(a_hi[rep].z, a_hi[rep].w);
            *reinterpret_cast<short8*>(&As[srow[rep] * 72 + skq]) =
                __builtin_bit_cast(short8, wvp);
            *reinterpret_cast<short8*>(&Bs[srow[rep] * 72 + skq]) = b_reg[rep];
        }
        __syncthreads();
        if (it < 15) {
            const int k1 = (it + 1) * 64;
#pragma unroll
            for (int rep = 0; rep < 4; ++rep) {
                const float* src = Af + (size_t)(m0 + srow[rep]) * 1024 + k1 + skq;
                a_lo[rep] = *reinterpret_cast<const float4*>(src);
                a_hi[rep] = *reinterpret_cast<const float4*>(src + 4);
                b_reg[rep] = ld8(Wt + (size_t)(n0 + srow[rep]) * 1024 + k1 + skq);
            }
        }
#pragma unroll
        for (int kk = 0; kk < 64; kk += 32) {
            short8 afr[4], bfr[4];
#pragma unroll
            for (int mi = 0; mi < 4; ++mi)
                afr[mi] = ld8(&As[(wr * 64 + mi * 16 + c) * 72 + kk + 8 * g]);
#pragma unroll
            for (int ni = 0; ni < 4; ++ni)
                bfr[ni] = ld8(&Bs[(wc * 64 + ni * 16 + c) * 72 + kk + 8 * g]);
#pragma unroll
            for (int mi = 0; mi < 4; ++mi)
#pragma unroll
                for (int ni = 0; ni < 4; ++ni)
                    acc[mi][ni] = __builtin_amdgcn_mfma_f32_16x16x32_bf16(
                        afr[mi], bfr[ni], acc[mi][ni], 0, 0, 0);
        }
        __syncthreads();
    }

#pragma unroll
    for (int mi = 0; mi < 4; ++mi) {
#pragma unroll
        for (int ni = 0; ni < 4; ++ni) {
            const int n = n0 + wc * 64 + ni * 16 + c;
            const float bb = bias[n];
#pragma unroll
            for (int j = 0; j < 4; ++j) {
                const int m = m0 + wr * 64 + mi * 16 + 4 * g + j;
                const int b = m >> 11, s = m & 2047;
                const ushort_t val = f2bf((acc[mi][ni][j] + bb) * qscale);
                if (isQ) {
                    Qr[((size_t)((b * 16 + (n >> 6)) * 2048 + s)) * 64 + (n & 63)] = val;
                } else if (n < 1024) {
                    Kr[((size_t)((b * 16 + (n >> 6)) * 2048 + s)) * 64 + (n & 63)] = val;
                } else {
                    const int np = n - 1024;
                    Vt[(size_t)((b * 16 + (np >> 6)) * 64 + (np & 63)) * 2048 + s] = val;
                }
            }
        }
    }
}

// ---------------------------------------------------------------------------
// Fallback projection (r3/r8-proven): used if ws_size is too small for prep.
// ---------------------------------------------------------------------------
__global__ __launch_bounds__(256)
void proj_gemm(const float* __restrict__ A, const float* __restrict__ W,
               const float* __restrict__ bias, int N,
               ushort_t* __restrict__ outRow, ushort_t* __restrict__ outT)
{
    __shared__ ushort_t As[128 * 72];
    __shared__ ushort_t Bt[128 * 72];

    const int t = threadIdx.x;
    const int lane = t & 63;
    const int wv = t >> 6;
    const int wr = wv >> 1, wc = wv & 1;
    const int c = lane & 15, g = lane >> 4;
    const int m0 = blockIdx.y * 128, n0 = blockIdx.x * 128;
    const float qscale = (outT == nullptr) ? SCL_F : 1.0f;

    f32x4 acc[4][4];
    const f32x4 zero4 = {0.f, 0.f, 0.f, 0.f};
#pragma unroll
    for (int mi = 0; mi < 4; ++mi)
#pragma unroll
        for (int ni = 0; ni < 4; ++ni) acc[mi][ni] = zero4;

    for (int it = 0; it < 16; ++it) {
        const int k0 = it * 64;
        {
            const int kq = (t & 15) * 4;
            int r = t >> 4;
#pragma unroll
            for (int rep = 0; rep < 8; ++rep, r += 16) {
                float4 v = *reinterpret_cast<const float4*>(
                    A + (size_t)(m0 + r) * 1024 + k0 + kq);
                ushort_t* dst = &As[r * 72 + kq];
                dst[0] = f2bf(v.x); dst[1] = f2bf(v.y);
                dst[2] = f2bf(v.z); dst[3] = f2bf(v.w);
            }
        }
        {
            const int nq = (t & 31) * 4;
            const int kr = t >> 5;
#pragma unroll
            for (int rep = 0; rep < 8; ++rep) {
                const int k = kr + 8 * rep;
                float4 v = *reinterpret_cast<const float4*>(
                    W + (size_t)(k0 + k) * N + n0 + nq);
                Bt[(nq + 0) * 72 + k] = f2bf(v.x);
                Bt[(nq + 1) * 72 + k] = f2bf(v.y);
                Bt[(nq + 2) * 72 + k] = f2bf(v.z);
                Bt[(nq + 3) * 72 + k] = f2bf(v.w);
            }
        }
        __syncthreads();
#pragma unroll
        for (int kk = 0; kk < 64; kk += 32) {
            short8 afr[4], bfr[4];
#pragma unroll
            for (int mi = 0; mi < 4; ++mi)
                afr[mi] = ld8(&As[(wr * 64 + mi * 16 + c) * 72 + kk + 8 * g]);
#pragma unroll
            for (int ni = 0; ni < 4; ++ni)
                bfr[ni] = ld8(&Bt[(wc * 64 + ni * 16 + c) * 72 + kk + 8 * g]);
#pragma unroll
            for (int mi = 0; mi < 4; ++mi)
#pragma unroll
                for (int ni = 0; ni < 4; ++ni)
                    acc[mi][ni] = __builtin_amdgcn_mfma_f32_16x16x32_bf16(
                        afr[mi], bfr[ni], acc[mi][ni], 0, 0, 0);
        }
        __syncthreads();
    }

#pragma unroll
    for (int mi = 0; mi < 4; ++mi) {
#pragma unroll
        for (int ni = 0; ni < 4; ++ni) {
            const int n = n0 + wc * 64 + ni * 16 + c;
            const float bb = bias[n];
#pragma unroll
            for (int j = 0; j < 4; ++j) {
                const int m = m0 + wr * 64 + mi * 16 + 4 * g + j;
                const int b = m >> 11, s = m & 2047;
                const ushort_t val = f2bf((acc[mi][ni][j] + bb) * qscale);
                if (outT != nullptr && n >= 1024) {
                    const int np = n - 1024;
                    const int hh = np >> 6, d = np & 63;
                    outT[(size_t)((b * 16 + hh) * 64 + d) * 2048 + s] = val;
                } else {
                    const int hh = n >> 6, d = n & 63;
                    outRow[((size_t)((b * 16 + hh) * 2048 + s)) * 64 + d] = val;
                }
            }
        }
    }
}

// ---------------------------------------------------------------------------
// Flash attention (r19 champion): 2-tile LDS pipeline, stats-as-MFMA,
// setprio'd MFMA clusters, XOR-swizzled LDS.
// ---------------------------------------------------------------------------
DEV void tile_compute(const ushort_t* __restrict__ Ks, const ushort_t* __restrict__ Vs,
                      const ushort_t* __restrict__ Sts, int c, int g,
                      const short8 (&bq)[2][2],
                      f32x4 (&accv)[2][4], f32x4 (&stat)[2])
{
    const f32x4 zero4 = {0.f, 0.f, 0.f, 0.f};
    const int kxor = (c & 7) << 3;
    const int vxor = (c & 7) << 2;

    short8 KC[2][2];
#pragma unroll
    for (int ct = 0; ct < 2; ++ct)
#pragma unroll
        for (int st = 0; st < 2; ++st)
            KC[ct][st] = ld8(&Ks[(ct * 16 + c) * 64 + ((st * 32 + 8 * g) ^ kxor)]);
    short8 VC[4];
#pragma unroll
    for (int dt = 0; dt < 4; ++dt) {
        const short4_t vlo = *reinterpret_cast<const short4_t*>(
            &Vs[(dt * 16 + c) * 32 + ((4 * g) ^ vxor)]);
        const short4_t vhi = *reinterpret_cast<const short4_t*>(
            &Vs[(dt * 16 + c) * 32 + ((4 * g + 16) ^ vxor)]);
        VC[dt] = __builtin_shufflevector(vlo, vhi, 0, 1, 2, 3, 4, 5, 6, 7);
    }
    const short4_t slo = *reinterpret_cast<const short4_t*>(
        &Sts[c * 32 + ((4 * g) ^ vxor)]);
    const short4_t shi = *reinterpret_cast<const short4_t*>(
        &Sts[c * 32 + ((4 * g + 16) ^ vxor)]);
    const short8 stf = __builtin_shufflevector(slo, shi, 0, 1, 2, 3, 4, 5, 6, 7);

    // QK^T (swapped): lane holds S^T[kv=16ct+4g+j][q=c] (already * SCL)
    f32x4 sc[2][2];
    __builtin_amdgcn_s_setprio(1);
#pragma unroll
    for (int qt = 0; qt < 2; ++qt)
#pragma unroll
        for (int ct = 0; ct < 2; ++ct) {
            f32x4 z = zero4;
            z = __builtin_amdgcn_mfma_f32_16x16x32_bf16(KC[ct][0], bq[qt][0], z, 0, 0, 0);
            z = __builtin_amdgcn_mfma_f32_16x16x32_bf16(KC[ct][1], bq[qt][1], z, 0, 0, 0);
            sc[qt][ct] = z;
        }
    __builtin_amdgcn_s_setprio(0);

    // fixed-max softmax: P = exp2(sc) -> bf16
    short8 pa[2];
#pragma unroll
    for (int qt = 0; qt < 2; ++qt) {
        float e[2][4];
#pragma unroll
        for (int ct = 0; ct < 2; ++ct)
#pragma unroll
            for (int j = 0; j < 4; ++j)
                e[ct][j] = fast_exp2(sc[qt][ct][j]);
        int4 w;
        w.x = (int)pk_bf16(e[0][0], e[0][1]);
        w.y = (int)pk_bf16(e[0][2], e[0][3]);
        w.z = (int)pk_bf16(e[1][0], e[1][1]);
        w.w = (int)pk_bf16(e[1][2], e[1][3]);
        pa[qt] = __builtin_bit_cast(short8, w);
    }

    // stats + PV^T (A operands gathered in the same kv-slot permutation as P)
    __builtin_amdgcn_s_setprio(1);
#pragma unroll
    for (int qt = 0; qt < 2; ++qt)
        stat[qt] = __builtin_amdgcn_mfma_f32_16x16x32_bf16(stf, pa[qt], stat[qt], 0, 0, 0);
#pragma unroll
    for (int dt = 0; dt < 4; ++dt) {
        accv[0][dt] = __builtin_amdgcn_mfma_f32_16x16x32_bf16(VC[dt], pa[0], accv[0][dt], 0, 0, 0);
        accv[1][dt] = __builtin_amdgcn_mfma_f32_16x16x32_bf16(VC[dt], pa[1], accv[1][dt], 0, 0, 0);
    }
    __builtin_amdgcn_s_setprio(0);
}

DEV void pair_body(const ushort_t* __restrict__ Kh, const ushort_t* __restrict__ Vh,
                   const float* __restrict__ crb, int kvA, int kvB,
                   const ushort_t* KsC0, const ushort_t* VsC0, const ushort_t* StC0,
                   const ushort_t* KsC1, const ushort_t* VsC1, const ushort_t* StC1,
                   ushort_t* KsN0, ushort_t* VsN0, ushort_t* StN0,
                   ushort_t* KsN1, ushort_t* VsN1, ushort_t* StN1,
                   int t, int c, int g, int rk, int ck, int rv, int cv,
                   int kaddr, int vaddr0, int vaddr1,
                   const short8 (&bq)[2][2],
                   f32x4 (&accv)[2][4], f32x4 (&stat)[2])
{
    // prefetch next two tiles (global -> reg); cr rows by threads t<128
    const short8 kregA = ld8(Kh + (size_t)(kvA + rk) * 64 + ck);
    const short8 vregA = ld8(Vh + (size_t)rv * 2048 + kvA + cv);
    const short8 kregB = ld8(Kh + (size_t)(kvB + rk) * 64 + ck);
    const short8 vregB = ld8(Vh + (size_t)rv * 2048 + kvB + cv);
    ushort_t crsh = 0; int staddr = 0;
    if (t < 128) {
        const int kvX = (t & 64) ? kvB : kvA;
        const int row = 1 + ((t >> 5) & 1);
        const float v = crb[(size_t)(kvX + (t & 31)) * 2 + (row - 1)];
        crsh = f2bf(v);
        staddr = row * 32 + ((t & 31) ^ ((row & 7) << 2));
    }
    __builtin_amdgcn_sched_barrier(0);

    // two independent tile computations (compiler interleaves for ILP)
    tile_compute(KsC0, VsC0, StC0, c, g, bq, accv, stat);
    tile_compute(KsC1, VsC1, StC1, c, g, bq, accv, stat);

    // write staged tiles into the next buffer group; one barrier per 64 kv
    *reinterpret_cast<short8*>(&KsN0[kaddr]) = kregA;
    *reinterpret_cast<short8*>(&KsN1[kaddr]) = kregB;
    *reinterpret_cast<short4_t*>(&VsN0[vaddr0]) = __builtin_shufflevector(vregA, vregA, 0, 1, 2, 3);
    *reinterpret_cast<short4_t*>(&VsN0[vaddr1]) = __builtin_shufflevector(vregA, vregA, 4, 5, 6, 7);
    *reinterpret_cast<short4_t*>(&VsN1[vaddr0]) = __builtin_shufflevector(vregB, vregB, 0, 1, 2, 3);
    *reinterpret_cast<short4_t*>(&VsN1[vaddr1]) = __builtin_shufflevector(vregB, vregB, 4, 5, 6, 7);
    if (t < 128) ((t & 64) ? StN1 : StN0)[staddr] = crsh;
    __syncthreads();
}

__global__ __launch_bounds__(256, 2)
void attn_kernel(const ushort_t* __restrict__ Qr, const ushort_t* __restrict__ Kr,
                 const ushort_t* __restrict__ Vt, const float* __restrict__ cr,
                 const float* __restrict__ Wmo, const float* __restrict__ bmo,
                 float* __restrict__ out)
{
    // shorts: K 4x2048 @0; V 4x2048 @8192; St 4x512 @16384. 36864 B total.
    __shared__ ushort_t smem[18432];
    ushort_t* K0 = smem;            ushort_t* K1 = smem + 2048;
    ushort_t* K2 = smem + 4096;     ushort_t* K3 = smem + 6144;
    ushort_t* V0 = smem + 8192;     ushort_t* V1 = smem + 10240;
    ushort_t* V2 = smem + 12288;    ushort_t* V3 = smem + 14336;
    ushort_t* S0 = smem + 16384;    ushort_t* S1 = smem + 16896;
    ushort_t* S2 = smem + 17408;    ushort_t* S3 = smem + 17920;

    const int t = threadIdx.x;
    const int w = t >> 6, lane = t & 63;
    const int c = lane & 15, g = lane >> 4;
    const int rk = t >> 3, ck = (t & 7) * 8;
    const int rv = t >> 2, cv = (t & 3) * 8;
    const int kaddr  = rk * 64 + (ck ^ ((rk & 7) << 3));
    const int vaddr0 = rv * 32 + (cv ^ ((rv & 7) << 2));
    const int vaddr1 = rv * 32 + ((cv + 4) ^ ((rv & 7) << 2));

    // XCD swizzle: gid%8 ~ XCD; each XCD sees 4 distinct (b,h) pairs.
    const int gid = blockIdx.x;
    const int bh = (gid & 7) + 8 * ((gid >> 3) & 3);
    const int xt = gid >> 5;
    const int b = bh >> 4, hh = bh & 15;
    const int qb = xt * 128 + w * 32;

    const ushort_t* Qh = Qr + (size_t)bh * (2048 * 64);
    const ushort_t* Kh = Kr + (size_t)bh * (2048 * 64);
    const ushort_t* Vh = Vt + (size_t)bh * (64 * 2048);
    const float*   crb = cr + (size_t)b * (2048 * 2);

    short8 bq[2][2];
#pragma unroll
    for (int qt = 0; qt < 2; ++qt)
#pragma unroll
        for (int st = 0; st < 2; ++st)
            bq[qt][st] = ld8(Qh + (size_t)(qb + qt * 16 + c) * 64 + st * 32 + 8 * g);

    f32x4 accv[2][4];
    f32x4 stat[2];
    const f32x4 zero4 = {0.f, 0.f, 0.f, 0.f};
#pragma unroll
    for (int qt = 0; qt < 2; ++qt) {
        stat[qt] = zero4;
#pragma unroll
        for (int dt = 0; dt < 4; ++dt) accv[qt][dt] = zero4;
    }

    // init static St rows (0 -> ones, 3..15 -> zero) for all 4 groups
    for (int idx = t; idx < 2048; idx += 256) {
        const int row = (idx >> 5) & 15;
        if (row != 1 && row != 2)
            smem[16384 + idx] = (row == 0) ? (ushort_t)0x3F80 : (ushort_t)0;
    }

    // prologue: stage tiles kv=0 (group0) and kv=32 (group1)
    {
        const short8 kA = ld8(Kh + (size_t)rk * 64 + ck);
        const short8 vA = ld8(Vh + (size_t)rv * 2048 + cv);
        const short8 kB = ld8(Kh + (size_t)(32 + rk) * 64 + ck);
        const short8 vB = ld8(Vh + (size_t)rv * 2048 + 32 + cv);
        *reinterpret_cast<short8*>(&K0[kaddr]) = kA;
        *reinterpret_cast<short8*>(&K1[kaddr]) = kB;
        *reinterpret_cast<short4_t*>(&V0[vaddr0]) = __builtin_shufflevector(vA, vA, 0, 1, 2, 3);
        *reinterpret_cast<short4_t*>(&V0[vaddr1]) = __builtin_shufflevector(vA, vA, 4, 5, 6, 7);
        *reinterpret_cast<short4_t*>(&V1[vaddr0]) = __builtin_shufflevector(vB, vB, 0, 1, 2, 3);
        *reinterpret_cast<short4_t*>(&V1[vaddr1]) = __builtin_shufflevector(vB, vB, 4, 5, 6, 7);
        if (t < 128) {
            const int kvX = (t & 64) ? 32 : 0;
            const int row = 1 + ((t >> 5) & 1);
            const float v = crb[(size_t)(kvX + (t & 31)) * 2 + (row - 1)];
            ((t & 64) ? S1 : S0)[row * 32 + ((t & 31) ^ ((row & 7) << 2))] = f2bf(v);
        }
    }
    __syncthreads();

    for (int i = 0; i < 16; ++i) {
        const int base = i * 128;
        pair_body(Kh, Vh, crb, base + 64, base + 96,
                  K0, V0, S0, K1, V1, S1,
                  K2, V2, S2, K3, V3, S3,
                  t, c, g, rk, ck, rv, cv, kaddr, vaddr0, vaddr1,
                  bq, accv, stat);
        pair_body(Kh, Vh, crb, (base + 128) & 2047, (base + 160) & 2047,
                  K2, V2, S2, K3, V3, S3,
                  K0, V0, S0, K1, V1, S1,
                  t, c, g, rk, ck, rv, cv, kaddr, vaddr0, vaddr1,
                  bq, accv, stat);
    }

    // stats live in lane (c, g=0): reg 0=l, 1=a0, 2=a1. Broadcast to all g.
    float lst[2], a0s[2], a1s[2];
#pragma unroll
    for (int qt = 0; qt < 2; ++qt) {
        lst[qt] = __shfl(stat[qt][0], c, 64);
        a0s[qt] = __shfl(stat[qt][1], c, 64);
        a1s[qt] = __shfl(stat[qt][2], c, 64);
    }

    // epilogue: accv[qt][dt] reg j -> q = qb+qt*16+c, d = dt*16+4g+j
#pragma unroll
    for (int qt = 0; qt < 2; ++qt) {
        const int q = qb + qt * 16 + c;
        const float inv = 1.f / lst[qt];
        const float a0 = a0s[qt] * inv, a1 = a1s[qt] * inv;
#pragma unroll
        for (int dt = 0; dt < 4; ++dt) {
            const int d = hh * 64 + dt * 16 + 4 * g;
            const float4 w0 = *reinterpret_cast<const float4*>(Wmo + d);
            const float4 w1 = *reinterpret_cast<const float4*>(Wmo + 1024 + d);
            const float4 bm = *reinterpret_cast<const float4*>(bmo + d);
            const size_t oidx = ((size_t)(b * 2048 + q)) * 1024 + d;
            float4 hv, mv;
            hv.x = accv[qt][dt][0] * inv; hv.y = accv[qt][dt][1] * inv;
            hv.z = accv[qt][dt][2] * inv; hv.w = accv[qt][dt][3] * inv;
            mv.x = a0 * w0.x + a1 * w1.x + bm.x;
            mv.y = a0 * w0.y + a1 * w1.y + bm.y;
            mv.z = a0 * w0.z + a1 * w1.z + bm.z;
            mv.w = a0 * w0.w + a1 * w1.w + bm.w;
            *reinterpret_cast<float4*>(out + oidx) = hv;
            *reinterpret_cast<float4*>(out + 4194304 + oidx) = mv;
        }
    }
}

// ---------------------------------------------------------------------------
extern "C" void kernel_launch(void* const* d_in, const int* in_sizes, int n_in,
                              void* d_out, int out_size, void* d_ws, size_t ws_size,
                              hipStream_t stream)
{
    const float* i1  = (const float*)d_in[0];
    const float* i2  = (const float*)d_in[1];
    const float* cr  = (const float*)d_in[2];
    const float* Wq  = (const float*)d_in[3];
    const float* bq  = (const float*)d_in[4];
    const float* Wkv = (const float*)d_in[5];
    const float* bkv = (const float*)d_in[6];
    const float* Wmo = (const float*)d_in[7];
    const float* bmo = (const float*)d_in[8];
    float* out = (float*)d_out;

    ushort_t* Qr = (ushort_t*)d_ws;          // [2,16,2048,64] bf16 (8 MB)
    ushort_t* Kr = Qr + 4194304;             // (8 MB)
    ushort_t* Vt = Kr + 4194304;             // (8 MB)

    // fast path: + Wqt (2 MB) + Wkvt (4 MB) = 30 MB of ws
    if (ws_size >= 31457280ULL) {
        ushort_t* Wqt  = Vt + 4194304;
        ushort_t* Wkvt = Wqt + 1048576;
        tcvt_bf16<<<dim3(16, 16), dim3(256), 0, stream>>>(Wq, Wqt, 1024, 1024);
        tcvt_bf16<<<dim3(32, 16), dim3(256), 0, stream>>>(Wkv, Wkvt, 1024, 2048);
        proj_all<<<dim3(768), dim3(256), 0, stream>>>(i1, i2, Wqt, Wkvt, bq, bkv, Qr, Kr, Vt);
    } else {
        proj_gemm<<<dim3(8, 32), dim3(256), 0, stream>>>(i1, Wq, bq, 1024, Qr, nullptr);
        proj_gemm<<<dim3(16, 32), dim3(256), 0, stream>>>(i2, Wkv, bkv, 2048, Kr, Vt);
    }
    attn_kernel<<<dim3(512), dim3(256), 0, stream>>>(Qr, Kr, Vt, cr, Wmo, bmo, out);
}

// Round 23
// 106.796 us; speedup vs baseline: 1.0874x; 1.0374x over previous
//
#include <hip/hip_runtime.h>
#include <hip/hip_bf16.h>

typedef __attribute__((ext_vector_type(8))) short short8;
typedef __attribute__((ext_vector_type(4))) short short4_t;
typedef __attribute__((ext_vector_type(4))) float f32x4;
typedef unsigned short ushort_t;

#define DEV __device__ __forceinline__

DEV ushort_t f2bf(float f) {
    unsigned u = __builtin_bit_cast(unsigned, f);
    u = u + 0x7fffu + ((u >> 16) & 1u);   // RNE
    return (ushort_t)(u >> 16);
}

DEV unsigned pk_bf16(float lo, float hi) {
    __hip_bfloat162 h = __float22bfloat162_rn(make_float2(lo, hi));
    unsigned u;
    __builtin_memcpy(&u, &h, sizeof(u));
    return u;
}

// raw v_exp_f32: single TRANS-pipe instr; exact in our argument range.
DEV float fast_exp2(float x) {
#if __has_builtin(__builtin_amdgcn_exp2f)
    return __builtin_amdgcn_exp2f(x);
#else
    float r;
    asm("v_exp_f32 %0, %1" : "=v"(r) : "v"(x));
    return r;
#endif
}

DEV short8 ld8(const ushort_t* p) { return *reinterpret_cast<const short8*>(p); }

#define SCL_F 0.18033688011112042f   // 0.125 * log2(e), prefolded into Q

// ---------------------------------------------------------------------------
// prep (single launch): W[K][N] f32 -> Wt[N][K] bf16, both weights.
//   blocks [0,256)   : Wq  [1024,1024] (16 nx x 16 ky)
//   blocks [256,768) : Wkv [1024,2048] (32 nx x 16 ky)
// Per-block transpose identical to the r19-proven tcvt_bf16.
// ---------------------------------------------------------------------------
__global__ __launch_bounds__(256)
void tcvt_all(const float* __restrict__ Wq, const float* __restrict__ Wkv,
              ushort_t* __restrict__ Wqt, ushort_t* __restrict__ Wkvt)
{
    __shared__ ushort_t tile[64][72];
    const int t = threadIdx.x;
    const int id = blockIdx.x;

    const float* W;
    ushort_t* Wt;
    int N, nx, ky;
    if (id < 256) {
        W = Wq; Wt = Wqt; N = 1024;
        nx = (id & 15) * 64; ky = (id >> 4) * 64;
    } else {
        const int r2 = id - 256;
        W = Wkv; Wt = Wkvt; N = 2048;
        nx = (r2 & 31) * 64; ky = (r2 >> 5) * 64;
    }

    const int r = t >> 2, q = (t & 3) * 16;
    const float* src = W + (size_t)(ky + r) * N + nx + q;
#pragma unroll
    for (int i = 0; i < 4; ++i) {
        const float4 v = *reinterpret_cast<const float4*>(src + 4 * i);
        tile[r][q + 4 * i + 0] = f2bf(v.x);
        tile[r][q + 4 * i + 1] = f2bf(v.y);
        tile[r][q + 4 * i + 2] = f2bf(v.z);
        tile[r][q + 4 * i + 3] = f2bf(v.w);
    }
    __syncthreads();
    short8 o0, o1;
#pragma unroll
    for (int i = 0; i < 8; ++i) {
        o0[i] = (short)tile[q + i][r];
        o1[i] = (short)tile[q + 8 + i][r];
    }
    ushort_t* dst = Wt + (size_t)(nx + r) * 1024 + ky + q;
    *reinterpret_cast<short8*>(dst) = o0;
    *reinterpret_cast<short8*>(dst + 8) = o1;
}

// ---------------------------------------------------------------------------
// Fused projections (r22 champion): nblk<8 -> Q = i1 @ WqT; else KV = i2 @
// WkvT. 1D grid (768) with XCD swizzle: all 24 blocks sharing an m0 A-panel
// land on one XCD, so the f32 A re-reads stay L2-resident. A converted during
// staging (pk RNE == f2bf RNE). Q pre-scaled by SCL_F.
// ---------------------------------------------------------------------------
__global__ __launch_bounds__(256, 2)
void proj_all(const float* __restrict__ i1, const float* __restrict__ i2,
              const ushort_t* __restrict__ Wqt, const ushort_t* __restrict__ Wkvt,
              const float* __restrict__ bqv, const float* __restrict__ bkv,
              ushort_t* __restrict__ Qr, ushort_t* __restrict__ Kr,
              ushort_t* __restrict__ Vt)
{
    __shared__ ushort_t As[128 * 72];
    __shared__ ushort_t Bs[128 * 72];

    const int t = threadIdx.x;
    const int lane = t & 63;
    const int wv = t >> 6;
    const int wr = wv >> 1, wc = wv & 1;
    const int c = lane & 15, g = lane >> 4;

    const int lid = blockIdx.x;
    const int m0i = (lid & 7) + 8 * ((lid >> 3) & 3);
    const int nblk = lid >> 5;
    const int m0 = m0i * 128;

    const float* Af;
    const ushort_t* Wt;
    const float* bias;
    int n0;
    if (nblk < 8) { Af = i1; Wt = Wqt;  bias = bqv; n0 = nblk * 128; }
    else          { Af = i2; Wt = Wkvt; bias = bkv; n0 = (nblk - 8) * 128; }
    const bool isQ = (nblk < 8);
    const float qscale = isQ ? SCL_F : 1.0f;

    f32x4 acc[4][4];
    const f32x4 zero4 = {0.f, 0.f, 0.f, 0.f};
#pragma unroll
    for (int mi = 0; mi < 4; ++mi)
#pragma unroll
        for (int ni = 0; ni < 4; ++ni) acc[mi][ni] = zero4;

    const int srow[4] = { (t + 0)   >> 3, (t + 256) >> 3, (t + 512) >> 3, (t + 768) >> 3 };
    const int skq     = (t & 7) * 8;

    float4 a_lo[4], a_hi[4];
    short8 b_reg[4];
#pragma unroll
    for (int rep = 0; rep < 4; ++rep) {
        const float* src = Af + (size_t)(m0 + srow[rep]) * 1024 + skq;
        a_lo[rep] = *reinterpret_cast<const float4*>(src);
        a_hi[rep] = *reinterpret_cast<const float4*>(src + 4);
        b_reg[rep] = ld8(Wt + (size_t)(n0 + srow[rep]) * 1024 + skq);
    }

    for (int it = 0; it < 16; ++it) {
#pragma unroll
        for (int rep = 0; rep < 4; ++rep) {
            int4 wvp;
            wvp.x = (int)pk_bf16(a_lo[rep].x, a_lo[rep].y);
            wvp.y = (int)pk_bf16(a_lo[rep].z, a_lo[rep].w);
            wvp.z = (int)pk_bf16(a_hi[rep].x, a_hi[rep].y);
            wvp.w = (int)pk_bf16(a_hi[rep].z, a_hi[rep].w);
            *reinterpret_cast<short8*>(&As[srow[rep] * 72 + skq]) =
                __builtin_bit_cast(short8, wvp);
            *reinterpret_cast<short8*>(&Bs[srow[rep] * 72 + skq]) = b_reg[rep];
        }
        __syncthreads();
        if (it < 15) {
            const int k1 = (it + 1) * 64;
#pragma unroll
            for (int rep = 0; rep < 4; ++rep) {
                const float* src = Af + (size_t)(m0 + srow[rep]) * 1024 + k1 + skq;
                a_lo[rep] = *reinterpret_cast<const float4*>(src);
                a_hi[rep] = *reinterpret_cast<const float4*>(src + 4);
                b_reg[rep] = ld8(Wt + (size_t)(n0 + srow[rep]) * 1024 + k1 + skq);
            }
        }
#pragma unroll
        for (int kk = 0; kk < 64; kk += 32) {
            short8 afr[4], bfr[4];
#pragma unroll
            for (int mi = 0; mi < 4; ++mi)
                afr[mi] = ld8(&As[(wr * 64 + mi * 16 + c) * 72 + kk + 8 * g]);
#pragma unroll
            for (int ni = 0; ni < 4; ++ni)
                bfr[ni] = ld8(&Bs[(wc * 64 + ni * 16 + c) * 72 + kk + 8 * g]);
#pragma unroll
            for (int mi = 0; mi < 4; ++mi)
#pragma unroll
                for (int ni = 0; ni < 4; ++ni)
                    acc[mi][ni] = __builtin_amdgcn_mfma_f32_16x16x32_bf16(
                        afr[mi], bfr[ni], acc[mi][ni], 0, 0, 0);
        }
        __syncthreads();
    }

#pragma unroll
    for (int mi = 0; mi < 4; ++mi) {
#pragma unroll
        for (int ni = 0; ni < 4; ++ni) {
            const int n = n0 + wc * 64 + ni * 16 + c;
            const float bb = bias[n];
#pragma unroll
            for (int j = 0; j < 4; ++j) {
                const int m = m0 + wr * 64 + mi * 16 + 4 * g + j;
                const int b = m >> 11, s = m & 2047;
                const ushort_t val = f2bf((acc[mi][ni][j] + bb) * qscale);
                if (isQ) {
                    Qr[((size_t)((b * 16 + (n >> 6)) * 2048 + s)) * 64 + (n & 63)] = val;
                } else if (n < 1024) {
                    Kr[((size_t)((b * 16 + (n >> 6)) * 2048 + s)) * 64 + (n & 63)] = val;
                } else {
                    const int np = n - 1024;
                    Vt[(size_t)((b * 16 + (np >> 6)) * 64 + (np & 63)) * 2048 + s] = val;
                }
            }
        }
    }
}

// ---------------------------------------------------------------------------
// Fallback projection (r3/r8-proven): used if ws_size is too small for prep.
// ---------------------------------------------------------------------------
__global__ __launch_bounds__(256)
void proj_gemm(const float* __restrict__ A, const float* __restrict__ W,
               const float* __restrict__ bias, int N,
               ushort_t* __restrict__ outRow, ushort_t* __restrict__ outT)
{
    __shared__ ushort_t As[128 * 72];
    __shared__ ushort_t Bt[128 * 72];

    const int t = threadIdx.x;
    const int lane = t & 63;
    const int wv = t >> 6;
    const int wr = wv >> 1, wc = wv & 1;
    const int c = lane & 15, g = lane >> 4;
    const int m0 = blockIdx.y * 128, n0 = blockIdx.x * 128;
    const float qscale = (outT == nullptr) ? SCL_F : 1.0f;

    f32x4 acc[4][4];
    const f32x4 zero4 = {0.f, 0.f, 0.f, 0.f};
#pragma unroll
    for (int mi = 0; mi < 4; ++mi)
#pragma unroll
        for (int ni = 0; ni < 4; ++ni) acc[mi][ni] = zero4;

    for (int it = 0; it < 16; ++it) {
        const int k0 = it * 64;
        {
            const int kq = (t & 15) * 4;
            int r = t >> 4;
#pragma unroll
            for (int rep = 0; rep < 8; ++rep, r += 16) {
                float4 v = *reinterpret_cast<const float4*>(
                    A + (size_t)(m0 + r) * 1024 + k0 + kq);
                ushort_t* dst = &As[r * 72 + kq];
                dst[0] = f2bf(v.x); dst[1] = f2bf(v.y);
                dst[2] = f2bf(v.z); dst[3] = f2bf(v.w);
            }
        }
        {
            const int nq = (t & 31) * 4;
            const int kr = t >> 5;
#pragma unroll
            for (int rep = 0; rep < 8; ++rep) {
                const int k = kr + 8 * rep;
                float4 v = *reinterpret_cast<const float4*>(
                    W + (size_t)(k0 + k) * N + n0 + nq);
                Bt[(nq + 0) * 72 + k] = f2bf(v.x);
                Bt[(nq + 1) * 72 + k] = f2bf(v.y);
                Bt[(nq + 2) * 72 + k] = f2bf(v.z);
                Bt[(nq + 3) * 72 + k] = f2bf(v.w);
            }
        }
        __syncthreads();
#pragma unroll
        for (int kk = 0; kk < 64; kk += 32) {
            short8 afr[4], bfr[4];
#pragma unroll
            for (int mi = 0; mi < 4; ++mi)
                afr[mi] = ld8(&As[(wr * 64 + mi * 16 + c) * 72 + kk + 8 * g]);
#pragma unroll
            for (int ni = 0; ni < 4; ++ni)
                bfr[ni] = ld8(&Bt[(wc * 64 + ni * 16 + c) * 72 + kk + 8 * g]);
#pragma unroll
            for (int mi = 0; mi < 4; ++mi)
#pragma unroll
                for (int ni = 0; ni < 4; ++ni)
                    acc[mi][ni] = __builtin_amdgcn_mfma_f32_16x16x32_bf16(
                        afr[mi], bfr[ni], acc[mi][ni], 0, 0, 0);
        }
        __syncthreads();
    }

#pragma unroll
    for (int mi = 0; mi < 4; ++mi) {
#pragma unroll
        for (int ni = 0; ni < 4; ++ni) {
            const int n = n0 + wc * 64 + ni * 16 + c;
            const float bb = bias[n];
#pragma unroll
            for (int j = 0; j < 4; ++j) {
                const int m = m0 + wr * 64 + mi * 16 + 4 * g + j;
                const int b = m >> 11, s = m & 2047;
                const ushort_t val = f2bf((acc[mi][ni][j] + bb) * qscale);
                if (outT != nullptr && n >= 1024) {
                    const int np = n - 1024;
                    const int hh = np >> 6, d = np & 63;
                    outT[(size_t)((b * 16 + hh) * 64 + d) * 2048 + s] = val;
                } else {
                    const int hh = n >> 6, d = n & 63;
                    outRow[((size_t)((b * 16 + hh) * 2048 + s)) * 64 + d] = val;
                }
            }
        }
    }
}

// ---------------------------------------------------------------------------
// Flash attention (r19 champion): 2-tile LDS pipeline, stats-as-MFMA,
// setprio'd MFMA clusters, XOR-swizzled LDS.
// ---------------------------------------------------------------------------
DEV void tile_compute(const ushort_t* __restrict__ Ks, const ushort_t* __restrict__ Vs,
                      const ushort_t* __restrict__ Sts, int c, int g,
                      const short8 (&bq)[2][2],
                      f32x4 (&accv)[2][4], f32x4 (&stat)[2])
{
    const f32x4 zero4 = {0.f, 0.f, 0.f, 0.f};
    const int kxor = (c & 7) << 3;
    const int vxor = (c & 7) << 2;

    short8 KC[2][2];
#pragma unroll
    for (int ct = 0; ct < 2; ++ct)
#pragma unroll
        for (int st = 0; st < 2; ++st)
            KC[ct][st] = ld8(&Ks[(ct * 16 + c) * 64 + ((st * 32 + 8 * g) ^ kxor)]);
    short8 VC[4];
#pragma unroll
    for (int dt = 0; dt < 4; ++dt) {
        const short4_t vlo = *reinterpret_cast<const short4_t*>(
            &Vs[(dt * 16 + c) * 32 + ((4 * g) ^ vxor)]);
        const short4_t vhi = *reinterpret_cast<const short4_t*>(
            &Vs[(dt * 16 + c) * 32 + ((4 * g + 16) ^ vxor)]);
        VC[dt] = __builtin_shufflevector(vlo, vhi, 0, 1, 2, 3, 4, 5, 6, 7);
    }
    const short4_t slo = *reinterpret_cast<const short4_t*>(
        &Sts[c * 32 + ((4 * g) ^ vxor)]);
    const short4_t shi = *reinterpret_cast<const short4_t*>(
        &Sts[c * 32 + ((4 * g + 16) ^ vxor)]);
    const short8 stf = __builtin_shufflevector(slo, shi, 0, 1, 2, 3, 4, 5, 6, 7);

    // QK^T (swapped): lane holds S^T[kv=16ct+4g+j][q=c] (already * SCL)
    f32x4 sc[2][2];
    __builtin_amdgcn_s_setprio(1);
#pragma unroll
    for (int qt = 0; qt < 2; ++qt)
#pragma unroll
        for (int ct = 0; ct < 2; ++ct) {
            f32x4 z = zero4;
            z = __builtin_amdgcn_mfma_f32_16x16x32_bf16(KC[ct][0], bq[qt][0], z, 0, 0, 0);
            z = __builtin_amdgcn_mfma_f32_16x16x32_bf16(KC[ct][1], bq[qt][1], z, 0, 0, 0);
            sc[qt][ct] = z;
        }
    __builtin_amdgcn_s_setprio(0);

    // fixed-max softmax: P = exp2(sc) -> bf16
    short8 pa[2];
#pragma unroll
    for (int qt = 0; qt < 2; ++qt) {
        float e[2][4];
#pragma unroll
        for (int ct = 0; ct < 2; ++ct)
#pragma unroll
            for (int j = 0; j < 4; ++j)
                e[ct][j] = fast_exp2(sc[qt][ct][j]);
        int4 w;
        w.x = (int)pk_bf16(e[0][0], e[0][1]);
        w.y = (int)pk_bf16(e[0][2], e[0][3]);
        w.z = (int)pk_bf16(e[1][0], e[1][1]);
        w.w = (int)pk_bf16(e[1][2], e[1][3]);
        pa[qt] = __builtin_bit_cast(short8, w);
    }

    // stats + PV^T (A operands gathered in the same kv-slot permutation as P)
    __builtin_amdgcn_s_setprio(1);
#pragma unroll
    for (int qt = 0; qt < 2; ++qt)
        stat[qt] = __builtin_amdgcn_mfma_f32_16x16x32_bf16(stf, pa[qt], stat[qt], 0, 0, 0);
#pragma unroll
    for (int dt = 0; dt < 4; ++dt) {
        accv[0][dt] = __builtin_amdgcn_mfma_f32_16x16x32_bf16(VC[dt], pa[0], accv[0][dt], 0, 0, 0);
        accv[1][dt] = __builtin_amdgcn_mfma_f32_16x16x32_bf16(VC[dt], pa[1], accv[1][dt], 0, 0, 0);
    }
    __builtin_amdgcn_s_setprio(0);
}

DEV void pair_body(const ushort_t* __restrict__ Kh, const ushort_t* __restrict__ Vh,
                   const float* __restrict__ crb, int kvA, int kvB,
                   const ushort_t* KsC0, const ushort_t* VsC0, const ushort_t* StC0,
                   const ushort_t* KsC1, const ushort_t* VsC1, const ushort_t* StC1,
                   ushort_t* KsN0, ushort_t* VsN0, ushort_t* StN0,
                   ushort_t* KsN1, ushort_t* VsN1, ushort_t* StN1,
                   int t, int c, int g, int rk, int ck, int rv, int cv,
                   int kaddr, int vaddr0, int vaddr1,
                   const short8 (&bq)[2][2],
                   f32x4 (&accv)[2][4], f32x4 (&stat)[2])
{
    // prefetch next two tiles (global -> reg); cr rows by threads t<128
    const short8 kregA = ld8(Kh + (size_t)(kvA + rk) * 64 + ck);
    const short8 vregA = ld8(Vh + (size_t)rv * 2048 + kvA + cv);
    const short8 kregB = ld8(Kh + (size_t)(kvB + rk) * 64 + ck);
    const short8 vregB = ld8(Vh + (size_t)rv * 2048 + kvB + cv);
    ushort_t crsh = 0; int staddr = 0;
    if (t < 128) {
        const int kvX = (t & 64) ? kvB : kvA;
        const int row = 1 + ((t >> 5) & 1);
        const float v = crb[(size_t)(kvX + (t & 31)) * 2 + (row - 1)];
        crsh = f2bf(v);
        staddr = row * 32 + ((t & 31) ^ ((row & 7) << 2));
    }
    __builtin_amdgcn_sched_barrier(0);

    // two independent tile computations (compiler interleaves for ILP)
    tile_compute(KsC0, VsC0, StC0, c, g, bq, accv, stat);
    tile_compute(KsC1, VsC1, StC1, c, g, bq, accv, stat);

    // write staged tiles into the next buffer group; one barrier per 64 kv
    *reinterpret_cast<short8*>(&KsN0[kaddr]) = kregA;
    *reinterpret_cast<short8*>(&KsN1[kaddr]) = kregB;
    *reinterpret_cast<short4_t*>(&VsN0[vaddr0]) = __builtin_shufflevector(vregA, vregA, 0, 1, 2, 3);
    *reinterpret_cast<short4_t*>(&VsN0[vaddr1]) = __builtin_shufflevector(vregA, vregA, 4, 5, 6, 7);
    *reinterpret_cast<short4_t*>(&VsN1[vaddr0]) = __builtin_shufflevector(vregB, vregB, 0, 1, 2, 3);
    *reinterpret_cast<short4_t*>(&VsN1[vaddr1]) = __builtin_shufflevector(vregB, vregB, 4, 5, 6, 7);
    if (t < 128) ((t & 64) ? StN1 : StN0)[staddr] = crsh;
    __syncthreads();
}

__global__ __launch_bounds__(256, 2)
void attn_kernel(const ushort_t* __restrict__ Qr, const ushort_t* __restrict__ Kr,
                 const ushort_t* __restrict__ Vt, const float* __restrict__ cr,
                 const float* __restrict__ Wmo, const float* __restrict__ bmo,
                 float* __restrict__ out)
{
    // shorts: K 4x2048 @0; V 4x2048 @8192; St 4x512 @16384. 36864 B total.
    __shared__ ushort_t smem[18432];
    ushort_t* K0 = smem;            ushort_t* K1 = smem + 2048;
    ushort_t* K2 = smem + 4096;     ushort_t* K3 = smem + 6144;
    ushort_t* V0 = smem + 8192;     ushort_t* V1 = smem + 10240;
    ushort_t* V2 = smem + 12288;    ushort_t* V3 = smem + 14336;
    ushort_t* S0 = smem + 16384;    ushort_t* S1 = smem + 16896;
    ushort_t* S2 = smem + 17408;    ushort_t* S3 = smem + 17920;

    const int t = threadIdx.x;
    const int w = t >> 6, lane = t & 63;
    const int c = lane & 15, g = lane >> 4;
    const int rk = t >> 3, ck = (t & 7) * 8;
    const int rv = t >> 2, cv = (t & 3) * 8;
    const int kaddr  = rk * 64 + (ck ^ ((rk & 7) << 3));
    const int vaddr0 = rv * 32 + (cv ^ ((rv & 7) << 2));
    const int vaddr1 = rv * 32 + ((cv + 4) ^ ((rv & 7) << 2));

    // XCD swizzle: gid%8 ~ XCD; each XCD sees 4 distinct (b,h) pairs.
    const int gid = blockIdx.x;
    const int bh = (gid & 7) + 8 * ((gid >> 3) & 3);
    const int xt = gid >> 5;
    const int b = bh >> 4, hh = bh & 15;
    const int qb = xt * 128 + w * 32;

    const ushort_t* Qh = Qr + (size_t)bh * (2048 * 64);
    const ushort_t* Kh = Kr + (size_t)bh * (2048 * 64);
    const ushort_t* Vh = Vt + (size_t)bh * (64 * 2048);
    const float*   crb = cr + (size_t)b * (2048 * 2);

    short8 bq[2][2];
#pragma unroll
    for (int qt = 0; qt < 2; ++qt)
#pragma unroll
        for (int st = 0; st < 2; ++st)
            bq[qt][st] = ld8(Qh + (size_t)(qb + qt * 16 + c) * 64 + st * 32 + 8 * g);

    f32x4 accv[2][4];
    f32x4 stat[2];
    const f32x4 zero4 = {0.f, 0.f, 0.f, 0.f};
#pragma unroll
    for (int qt = 0; qt < 2; ++qt) {
        stat[qt] = zero4;
#pragma unroll
        for (int dt = 0; dt < 4; ++dt) accv[qt][dt] = zero4;
    }

    // init static St rows (0 -> ones, 3..15 -> zero) for all 4 groups
    for (int idx = t; idx < 2048; idx += 256) {
        const int row = (idx >> 5) & 15;
        if (row != 1 && row != 2)
            smem[16384 + idx] = (row == 0) ? (ushort_t)0x3F80 : (ushort_t)0;
    }

    // prologue: stage tiles kv=0 (group0) and kv=32 (group1)
    {
        const short8 kA = ld8(Kh + (size_t)rk * 64 + ck);
        const short8 vA = ld8(Vh + (size_t)rv * 2048 + cv);
        const short8 kB = ld8(Kh + (size_t)(32 + rk) * 64 + ck);
        const short8 vB = ld8(Vh + (size_t)rv * 2048 + 32 + cv);
        *reinterpret_cast<short8*>(&K0[kaddr]) = kA;
        *reinterpret_cast<short8*>(&K1[kaddr]) = kB;
        *reinterpret_cast<short4_t*>(&V0[vaddr0]) = __builtin_shufflevector(vA, vA, 0, 1, 2, 3);
        *reinterpret_cast<short4_t*>(&V0[vaddr1]) = __builtin_shufflevector(vA, vA, 4, 5, 6, 7);
        *reinterpret_cast<short4_t*>(&V1[vaddr0]) = __builtin_shufflevector(vB, vB, 0, 1, 2, 3);
        *reinterpret_cast<short4_t*>(&V1[vaddr1]) = __builtin_shufflevector(vB, vB, 4, 5, 6, 7);
        if (t < 128) {
            const int kvX = (t & 64) ? 32 : 0;
            const int row = 1 + ((t >> 5) & 1);
            const float v = crb[(size_t)(kvX + (t & 31)) * 2 + (row - 1)];
            ((t & 64) ? S1 : S0)[row * 32 + ((t & 31) ^ ((row & 7) << 2))] = f2bf(v);
        }
    }
    __syncthreads();

    for (int i = 0; i < 16; ++i) {
        const int base = i * 128;
        pair_body(Kh, Vh, crb, base + 64, base + 96,
                  K0, V0, S0, K1, V1, S1,
                  K2, V2, S2, K3, V3, S3,
                  t, c, g, rk, ck, rv, cv, kaddr, vaddr0, vaddr1,
                  bq, accv, stat);
        pair_body(Kh, Vh, crb, (base + 128) & 2047, (base + 160) & 2047,
                  K2, V2, S2, K3, V3, S3,
                  K0, V0, S0, K1, V1, S1,
                  t, c, g, rk, ck, rv, cv, kaddr, vaddr0, vaddr1,
                  bq, accv, stat);
    }

    // stats live in lane (c, g=0): reg 0=l, 1=a0, 2=a1. Broadcast to all g.
    float lst[2], a0s[2], a1s[2];
#pragma unroll
    for (int qt = 0; qt < 2; ++qt) {
        lst[qt] = __shfl(stat[qt][0], c, 64);
        a0s[qt] = __shfl(stat[qt][1], c, 64);
        a1s[qt] = __shfl(stat[qt][2], c, 64);
    }

    // epilogue: accv[qt][dt] reg j -> q = qb+qt*16+c, d = dt*16+4g+j
#pragma unroll
    for (int qt = 0; qt < 2; ++qt) {
        const int q = qb + qt * 16 + c;
        const float inv = 1.f / lst[qt];
        const float a0 = a0s[qt] * inv, a1 = a1s[qt] * inv;
#pragma unroll
        for (int dt = 0; dt < 4; ++dt) {
            const int d = hh * 64 + dt * 16 + 4 * g;
            const float4 w0 = *reinterpret_cast<const float4*>(Wmo + d);
            const float4 w1 = *reinterpret_cast<const float4*>(Wmo + 1024 + d);
            const float4 bm = *reinterpret_cast<const float4*>(bmo + d);
            const size_t oidx = ((size_t)(b * 2048 + q)) * 1024 + d;
            float4 hv, mv;
            hv.x = accv[qt][dt][0] * inv; hv.y = accv[qt][dt][1] * inv;
            hv.z = accv[qt][dt][2] * inv; hv.w = accv[qt][dt][3] * inv;
            mv.x = a0 * w0.x + a1 * w1.x + bm.x;
            mv.y = a0 * w0.y + a1 * w1.y + bm.y;
            mv.z = a0 * w0.z + a1 * w1.z + bm.z;
            mv.w = a0 * w0.w + a1 * w1.w + bm.w;
            *reinterpret_cast<float4*>(out + oidx) = hv;
            *reinterpret_cast<float4*>(out + 4194304 + oidx) = mv;
        }
    }
}

// ---------------------------------------------------------------------------
extern "C" void kernel_launch(void* const* d_in, const int* in_sizes, int n_in,
                              void* d_out, int out_size, void* d_ws, size_t ws_size,
                              hipStream_t stream)
{
    const float* i1  = (const float*)d_in[0];
    const float* i2  = (const float*)d_in[1];
    const float* cr  = (const float*)d_in[2];
    const float* Wq  = (const float*)d_in[3];
    const float* bq  = (const float*)d_in[4];
    const float* Wkv = (const float*)d_in[5];
    const float* bkv = (const float*)d_in[6];
    const float* Wmo = (const float*)d_in[7];
    const float* bmo = (const float*)d_in[8];
    float* out = (float*)d_out;

    ushort_t* Qr = (ushort_t*)d_ws;          // [2,16,2048,64] bf16 (8 MB)
    ushort_t* Kr = Qr + 4194304;             // (8 MB)
    ushort_t* Vt = Kr + 4194304;             // (8 MB)

    // fast path: + Wqt (2 MB) + Wkvt (4 MB) = 30 MB of ws
    if (ws_size >= 31457280ULL) {
        ushort_t* Wqt  = Vt + 4194304;
        ushort_t* Wkvt = Wqt + 1048576;
        tcvt_all<<<dim3(768), dim3(256), 0, stream>>>(Wq, Wkv, Wqt, Wkvt);
        proj_all<<<dim3(768), dim3(256), 0, stream>>>(i1, i2, Wqt, Wkvt, bq, bkv, Qr, Kr, Vt);
    } else {
        proj_gemm<<<dim3(8, 32), dim3(256), 0, stream>>>(i1, Wq, bq, 1024, Qr, nullptr);
        proj_gemm<<<dim3(16, 32), dim3(256), 0, stream>>>(i2, Wkv, bkv, 2048, Kr, Vt);
    }
    attn_kernel<<<dim3(512), dim3(256), 0, stream>>>(Qr, Kr, Vt, cr, Wmo, bmo, out);
}